// Round 12
// baseline (103.617 us; speedup 1.0000x reference)
//
#include <hip/hip_runtime.h>
#include <math.h>

#define D 256
#define K2 512          // 2*D
#define BATCH 1024      // n2
#define N1 11264        // n1 = B*(1+10)
#define S0 25
#define S1 10

typedef __bf16 bf16x8 __attribute__((ext_vector_type(8)));
typedef __bf16 bf16x4 __attribute__((ext_vector_type(4)));
typedef float  f32x4  __attribute__((ext_vector_type(4)));

// ---------------------------------------------------------------------------
// fused_layer0 (512 threads, RB=32, BK=32): per block of 32 output rows:
//   phase 1 (gather): 8 waves x 4 rows each: self + mean of 25 neighbor fp32
//     rows -> bf16 -> swizzled full-K LDS A-tile [32][512].
//   phase 2 (GEMM): 16 k-tiles of 32; wave (wr,wc)=(w>>2,w&3) computes rows
//     [16wr,16wr+16) x cols [64wc,64wc+64); B staged from fp32 W0 with inline
//     bf16 cvt (reg-prefetched).
//   epilogue: bias + relu + row-l2norm -> h1b (bf16).
// WHY 512 threads (R11 lesson): occupancy was grid-capped - 352 blocks of 4
// waves = 5.5 waves/CU no matter the LDS. 512-thread blocks put 11 waves/CU
// on the SAME 352-block grid (prep's 13-wave regime = 2.66 TB/s) with no
// extra W0 traffic. Gather serial row-chains per wave also halve (4 vs 8).
// Fragment mapping (m89): A/B lane l: row/col=l&15, k=(l>>4)*8+i.
// C/D: col=l&15, row=(l>>4)*4+reg.
// ---------------------------------------------------------------------------
__global__ __launch_bounds__(512, 2) void fused_layer0(
        const float* __restrict__ feat, const float* __restrict__ W0,
        const float* __restrict__ b0, const int* __restrict__ nodes2,
        const int* __restrict__ neigh2, const int* __restrict__ neigh1,
        __bf16* __restrict__ h1b) {
    __shared__ __bf16 Atile[32 * 512];   // 32KB, swizzled granules of 8 bf16
    __shared__ __bf16 Bs[256 * 32];      // 16KB: [cg 0..15][kc 0..3][lo 0..15]
    __shared__ float ssLDS[4][32];
    __shared__ float invLDS[32];

    const int tid = threadIdx.x;
    const int lane = tid & 63;
    const int w = tid >> 6;           // 0..7
    const int wr = w >> 2;            // row-group 0..1
    const int wc = w & 3;             // col-group 0..3
    const int rl = lane & 15;
    const int g = lane >> 4;
    const int row0 = blockIdx.x * 32;

    // ---- B prologue loads (k0 = 0), fp32, 2 slots x 32B per thread ----
    float4 rb0[2], rb1[2];
#pragma unroll
    for (int s = 0; s < 2; ++s) {
        int i = tid + s * 512;
        int cg = i >> 6, kc = (i >> 4) & 3, lo = i & 15;
        const float* p = W0 + (size_t)(cg * 16 + lo) * K2 + kc * 8;
        rb0[s] = *(const float4*)p;
        rb1[s] = *(const float4*)(p + 4);
    }

    // ---- gather phase: wave w handles rows [4w, 4w+4) ----
#pragma unroll 1
    for (int r = w * 4; r < w * 4 + 4; ++r) {
        const int gr = row0 + r;
        const int self_idx = (gr < BATCH) ? nodes2[gr] : neigh2[gr - BATCH];
        const int* nb = neigh1 + (size_t)gr * S0;
        int idx[S0];
#pragma unroll
        for (int j = 0; j < S0; ++j) idx[j] = nb[j];
        float4 sv = ((const float4*)(feat + (size_t)self_idx * D))[lane];
        float4 v[S0];
#pragma unroll
        for (int j = 0; j < S0; ++j)
            v[j] = ((const float4*)(feat + (size_t)idx[j] * D))[lane];
        __builtin_amdgcn_sched_barrier(0);
        float4 acc = make_float4(0.f, 0.f, 0.f, 0.f);
#pragma unroll
        for (int j = 0; j < S0; ++j) {
            acc.x += v[j].x; acc.y += v[j].y; acc.z += v[j].z; acc.w += v[j].w;
        }
        const float s25 = 1.0f / 25.0f;
        bf16x4 svb = { (__bf16)sv.x, (__bf16)sv.y, (__bf16)sv.z, (__bf16)sv.w };
        bf16x4 avb = { (__bf16)(acc.x * s25), (__bf16)(acc.y * s25),
                       (__bf16)(acc.z * s25), (__bf16)(acc.w * s25) };
        // self dims [4l,4l+4) -> granule l>>1 (half l&1); agg dims +256 -> +32 granules
        const int sw = r & 7;
        const int gs = (lane >> 1) ^ sw;
        const int ga = (32 + (lane >> 1)) ^ sw;
        *(bf16x4*)(Atile + (size_t)r * 512 + gs * 8 + (lane & 1) * 4) = svb;
        *(bf16x4*)(Atile + (size_t)r * 512 + ga * 8 + (lane & 1) * 4) = avb;
    }
    __syncthreads();

    // ---- GEMM phase: 16 k-tiles of 32; wave (wr,wc) owns 16x64 output ----
    f32x4 acc[4];
#pragma unroll
    for (int nf = 0; nf < 4; ++nf) acc[nf] = (f32x4){0.f, 0.f, 0.f, 0.f};

    const int arow = wr * 16 + rl;

    for (int k0 = 0; k0 < K2; k0 += 32) {
        // write Bs from prefetched fp32 regs with inline cvt (linear in tid)
#pragma unroll
        for (int s = 0; s < 2; ++s) {
            int i = tid + s * 512;
            bf16x8 bv;
            bv[0] = (__bf16)rb0[s].x; bv[1] = (__bf16)rb0[s].y;
            bv[2] = (__bf16)rb0[s].z; bv[3] = (__bf16)rb0[s].w;
            bv[4] = (__bf16)rb1[s].x; bv[5] = (__bf16)rb1[s].y;
            bv[6] = (__bf16)rb1[s].z; bv[7] = (__bf16)rb1[s].w;
            *(bf16x8*)(Bs + (size_t)i * 8) = bv;
        }
        __syncthreads();
        if (k0 + 32 < K2) {
#pragma unroll
            for (int s = 0; s < 2; ++s) {
                int i = tid + s * 512;
                int cg = i >> 6, kc = (i >> 4) & 3, lo = i & 15;
                const float* p = W0 + (size_t)(cg * 16 + lo) * K2 + (k0 + 32) + kc * 8;
                rb0[s] = *(const float4*)p;
                rb1[s] = *(const float4*)(p + 4);
            }
        }
        {
            const int gA = (k0 >> 3) + g;   // granule index within a row
            bf16x8 af = *(const bf16x8*)(Atile + (size_t)arow * 512 +
                                         (size_t)(gA ^ (arow & 7)) * 8);
            bf16x8 bfr[4];
#pragma unroll
            for (int nf = 0; nf < 4; ++nf)
                bfr[nf] = *(const bf16x8*)(Bs + ((size_t)((wc * 4 + nf) * 4 + g) * 16 + rl) * 8);
#pragma unroll
            for (int nf = 0; nf < 4; ++nf)
                acc[nf] = __builtin_amdgcn_mfma_f32_16x16x32_bf16(af, bfr[nf], acc[nf], 0, 0, 0);
        }
        __syncthreads();
    }

    // ---- epilogue: bias + relu + row L2 norm (cross-wc via LDS) + store bf16 ----
    float bv[4];
#pragma unroll
    for (int nf = 0; nf < 4; ++nf) bv[nf] = b0[wc * 64 + nf * 16 + rl];

    float ss0 = 0.f, ss1 = 0.f, ss2 = 0.f, ss3 = 0.f;
#pragma unroll
    for (int nf = 0; nf < 4; ++nf) {
        float v0 = fmaxf(acc[nf][0] + bv[nf], 0.f);
        float v1 = fmaxf(acc[nf][1] + bv[nf], 0.f);
        float v2 = fmaxf(acc[nf][2] + bv[nf], 0.f);
        float v3 = fmaxf(acc[nf][3] + bv[nf], 0.f);
        acc[nf][0] = v0; acc[nf][1] = v1;
        acc[nf][2] = v2; acc[nf][3] = v3;
        ss0 += v0 * v0; ss1 += v1 * v1; ss2 += v2 * v2; ss3 += v3 * v3;
    }
#pragma unroll
    for (int m = 1; m < 16; m <<= 1) {
        ss0 += __shfl_xor(ss0, m);
        ss1 += __shfl_xor(ss1, m);
        ss2 += __shfl_xor(ss2, m);
        ss3 += __shfl_xor(ss3, m);
    }
    float ssv = (rl == 0) ? ss0 : (rl == 1) ? ss1 : (rl == 2) ? ss2 : ss3;
    if (rl < 4) ssLDS[wc][wr * 16 + g * 4 + rl] = ssv;
    __syncthreads();
    if (tid < 32) {
        float t = ssLDS[0][tid] + ssLDS[1][tid] + ssLDS[2][tid] + ssLDS[3][tid];
        invLDS[tid] = (t > 0.f) ? rsqrtf(t) : 1.0f;
    }
    __syncthreads();
#pragma unroll
    for (int j = 0; j < 4; ++j) {
        const int row = wr * 16 + g * 4 + j;
        const float inv = invLDS[row];
#pragma unroll
        for (int nf = 0; nf < 4; ++nf)
            h1b[(size_t)(row0 + row) * D + wc * 64 + nf * 16 + rl] =
                (__bf16)(acc[nf][j] * inv);
    }
}

// ---------------------------------------------------------------------------
// fused_layer1 (unchanged, ~9-10us): Out[1024][256] = l2norm(relu(X1 @ W1^T
// + b1)), X1 row i = [h1[i] | mean_j h1[1024+i*10+j]] built on the fly in
// A-staging (h1 bf16). B staged from fp32 W1 with inline cvt + reg prefetch.
// ---------------------------------------------------------------------------
__global__ __launch_bounds__(256, 2) void fused_layer1(
        const __bf16* __restrict__ h1, const float* __restrict__ W1,
        const float* __restrict__ b1, float* __restrict__ Out) {
    constexpr int RB = 32;
    __shared__ __bf16 As[RB * 64];
    __shared__ __bf16 Bs[256 * 64];
    __shared__ float ssLDS[4][RB];
    __shared__ float invLDS[RB];

    const int tid = threadIdx.x;
    const int row0 = blockIdx.x * RB;
    const int lane = tid & 63;
    const int w = tid >> 6;
    const int rl = lane & 15;
    const int g = lane >> 4;
    const int rg = tid >> 7, kc8 = (tid >> 4) & 7, lo = tid & 15;
    const int grow = row0 + rg * 16 + lo;

    // B prologue (k0 = 0)
    float4 rb0[8], rb1[8];
#pragma unroll
    for (int s = 0; s < 8; ++s) {
        int i = tid + s * 256;
        int cg = i >> 7, kc = (i >> 4) & 7, blo = i & 15;
        const float* p = W1 + (size_t)(cg * 16 + blo) * K2 + kc * 8;
        rb0[s] = *(const float4*)p;
        rb1[s] = *(const float4*)(p + 4);
    }

    f32x4 acc[2][4];
#pragma unroll
    for (int rf = 0; rf < 2; ++rf)
#pragma unroll
        for (int nf = 0; nf < 4; ++nf) acc[rf][nf] = (f32x4){0.f, 0.f, 0.f, 0.f};

    for (int k0 = 0; k0 < K2; k0 += 64) {
        // fused A-staging (build X1 tile on the fly)
        bf16x8 av;
        if (k0 < 256) {
            av = *(const bf16x8*)(h1 + (size_t)grow * D + k0 + kc8 * 8);
        } else {
            float f[8];
#pragma unroll
            for (int e = 0; e < 8; ++e) f[e] = 0.f;
            const __bf16* base = h1 + (size_t)(BATCH + grow * S1) * D + (k0 - 256) + kc8 * 8;
#pragma unroll
            for (int j = 0; j < S1; ++j) {
                bf16x8 vv = *(const bf16x8*)(base + (size_t)j * D);
#pragma unroll
                for (int e = 0; e < 8; ++e) f[e] += (float)vv[e];
            }
#pragma unroll
            for (int e = 0; e < 8; ++e) av[e] = (__bf16)(f[e] * 0.1f);
        }
        *(bf16x8*)(As + (size_t)tid * 8) = av;
        // B-staging from prefetched regs with cvt
#pragma unroll
        for (int s = 0; s < 8; ++s) {
            int i = tid + s * 256;
            bf16x8 bb;
            bb[0] = (__bf16)rb0[s].x; bb[1] = (__bf16)rb0[s].y;
            bb[2] = (__bf16)rb0[s].z; bb[3] = (__bf16)rb0[s].w;
            bb[4] = (__bf16)rb1[s].x; bb[5] = (__bf16)rb1[s].y;
            bb[6] = (__bf16)rb1[s].z; bb[7] = (__bf16)rb1[s].w;
            *(bf16x8*)(Bs + (size_t)i * 8) = bb;
        }
        __syncthreads();
        if (k0 + 64 < K2) {
#pragma unroll
            for (int s = 0; s < 8; ++s) {
                int i = tid + s * 256;
                int cg = i >> 7, kc = (i >> 4) & 7, blo = i & 15;
                const float* p = W1 + (size_t)(cg * 16 + blo) * K2 + (k0 + 64) + kc * 8;
                rb0[s] = *(const float4*)p;
                rb1[s] = *(const float4*)(p + 4);
            }
        }
#pragma unroll
        for (int kf = 0; kf < 2; ++kf) {
            const int kc = kf * 4 + g;
            bf16x8 af[2], bfr[4];
#pragma unroll
            for (int rf = 0; rf < 2; ++rf)
                af[rf] = *(const bf16x8*)(As + ((size_t)(rf * 8 + kc) * 16 + rl) * 8);
#pragma unroll
            for (int nf = 0; nf < 4; ++nf)
                bfr[nf] = *(const bf16x8*)(Bs + ((size_t)((w * 4 + nf) * 8 + kc) * 16 + rl) * 8);
#pragma unroll
            for (int rf = 0; rf < 2; ++rf)
#pragma unroll
                for (int nf = 0; nf < 4; ++nf)
                    acc[rf][nf] = __builtin_amdgcn_mfma_f32_16x16x32_bf16(
                        af[rf], bfr[nf], acc[rf][nf], 0, 0, 0);
        }
        __syncthreads();
    }

    float bv[4];
#pragma unroll
    for (int nf = 0; nf < 4; ++nf) bv[nf] = b1[w * 64 + nf * 16 + rl];

#pragma unroll
    for (int rf = 0; rf < 2; ++rf) {
        float ss0 = 0.f, ss1 = 0.f, ss2 = 0.f, ss3 = 0.f;
#pragma unroll
        for (int nf = 0; nf < 4; ++nf) {
            float v0 = fmaxf(acc[rf][nf][0] + bv[nf], 0.f);
            float v1 = fmaxf(acc[rf][nf][1] + bv[nf], 0.f);
            float v2 = fmaxf(acc[rf][nf][2] + bv[nf], 0.f);
            float v3 = fmaxf(acc[rf][nf][3] + bv[nf], 0.f);
            acc[rf][nf][0] = v0; acc[rf][nf][1] = v1;
            acc[rf][nf][2] = v2; acc[rf][nf][3] = v3;
            ss0 += v0 * v0; ss1 += v1 * v1; ss2 += v2 * v2; ss3 += v3 * v3;
        }
#pragma unroll
        for (int m = 1; m < 16; m <<= 1) {
            ss0 += __shfl_xor(ss0, m);
            ss1 += __shfl_xor(ss1, m);
            ss2 += __shfl_xor(ss2, m);
            ss3 += __shfl_xor(ss3, m);
        }
        float ssv = (rl == 0) ? ss0 : (rl == 1) ? ss1 : (rl == 2) ? ss2 : ss3;
        if (rl < 4) ssLDS[w][rf * 16 + g * 4 + rl] = ssv;
    }
    __syncthreads();
    if (tid < RB) {
        float t = ssLDS[0][tid] + ssLDS[1][tid] + ssLDS[2][tid] + ssLDS[3][tid];
        invLDS[tid] = (t > 0.f) ? rsqrtf(t) : 1.0f;
    }
    __syncthreads();
#pragma unroll
    for (int rf = 0; rf < 2; ++rf)
#pragma unroll
        for (int j = 0; j < 4; ++j) {
            const int row = rf * 16 + g * 4 + j;
            const float inv = invLDS[row];
#pragma unroll
            for (int nf = 0; nf < 4; ++nf)
                Out[(size_t)(row0 + row) * D + w * 64 + nf * 16 + rl] = acc[rf][nf][j] * inv;
        }
}

// ---------------------------------------------------------------------------
extern "C" void kernel_launch(void* const* d_in, const int* in_sizes, int n_in,
                              void* d_out, int out_size, void* d_ws, size_t ws_size,
                              hipStream_t stream) {
    const float* features = (const float*)d_in[0];
    const float* W0       = (const float*)d_in[1];
    const float* b0       = (const float*)d_in[2];
    const float* W1       = (const float*)d_in[3];
    const float* b1       = (const float*)d_in[4];
    const int*   nodes2   = (const int*)d_in[5];
    const int*   neigh2   = (const int*)d_in[6];
    const int*   neigh1   = (const int*)d_in[7];
    float* out = (float*)d_out;

    __bf16* h1b = (__bf16*)d_ws;   // 11264*256*2 = 5.75 MB

    fused_layer0<<<N1 / 32, 512, 0, stream>>>(features, W0, b0, nodes2, neigh2,
                                              neigh1, h1b);
    fused_layer1<<<BATCH / 32, 256, 0, stream>>>(h1b, W1, b1, out);
}

// Round 13
// 102.725 us; speedup vs baseline: 1.0087x; 1.0087x over previous
//
#include <hip/hip_runtime.h>
#include <math.h>

#define D 256
#define K2 512          // 2*D
#define BATCH 1024      // n2
#define N1 11264        // n1 = B*(1+10)
#define S0 25
#define S1 10

typedef __bf16 bf16x8 __attribute__((ext_vector_type(8)));
typedef __bf16 bf16x4 __attribute__((ext_vector_type(4)));
typedef float  f32x4  __attribute__((ext_vector_type(4)));

#define WG __HIP_MEMORY_SCOPE_WORKGROUP

// ---------------------------------------------------------------------------
// fused_layer0_pc: producer/consumer wave specialization (R12 lesson: the
// block-wide gather->GEMM phase structure starves the memory queue during
// GEMM; occupancy/MLP/LDS probes all null). 512 threads:
//   waves 0-3 (producers): gather rows [8w,8w+8) (self + mean of 25 fp32
//     rows) -> bf16 -> swizzled full-K Atile[32][512]; release rowcnt++ per
//     row; then EXIT.
//   waves 4-7 (consumers): stage Bs[0], spin on rowcnt==32 (LDS acquire),
//     then 16 k-tiles of 32 with double-buffered Bs (one consumer-only
//     round-barrier per tile, LDS atomic - no block barrier, no L2 traffic),
//     fused bias+relu+l2norm epilogue -> h1b (bf16).
// 2 blocks/CU (LDS 66KB <= 80KB, VGPR capped 128 via launch_bounds(512,4)):
// each CU keeps ~8 producer waves feeding the HBM queue continuously while
// consumer waves MFMA - gather and GEMM overlap WITHIN the CU.
// Deadlock-free: producers never wait on consumers; round-barrier is
// consumer-only; the single __syncthreads happens before role divergence.
// Fragment mapping (m89): A/B lane l: row/col=l&15, k=(l>>4)*8+i.
// C/D: col=l&15, row=(l>>4)*4+reg.
// ---------------------------------------------------------------------------
__global__ __launch_bounds__(512, 4) void fused_layer0_pc(
        const float* __restrict__ feat, const float* __restrict__ W0,
        const float* __restrict__ b0, const int* __restrict__ nodes2,
        const int* __restrict__ neigh2, const int* __restrict__ neigh1,
        __bf16* __restrict__ h1b) {
    __shared__ __bf16 Atile[32 * 512];     // 32KB, swizzled granules of 8 bf16
    __shared__ __bf16 Bs[2][256 * 32];     // 2x16KB, [cg 0..15][kc 0..3][lo 0..15]
    __shared__ float ssLDS[4][32];
    __shared__ int rowcnt;                 // rows gathered (0..32)
    __shared__ int rbar;                   // consumer round barrier

    const int tid = threadIdx.x;
    const int lane = tid & 63;
    const int w = tid >> 6;                // 0..7
    const int rl = lane & 15;
    const int g = lane >> 4;
    const int row0 = blockIdx.x * 32;

    if (tid == 0) { rowcnt = 0; rbar = 0; }
    __syncthreads();   // only block-wide barrier; all threads alive

    if (w < 4) {
        // ================= producers: waves 0..3, rows [8w, 8w+8) =========
#pragma unroll 1
        for (int r = w * 8; r < w * 8 + 8; ++r) {
            const int gr = row0 + r;
            const int self_idx = (gr < BATCH) ? nodes2[gr] : neigh2[gr - BATCH];
            const int* nb = neigh1 + (size_t)gr * S0;
            int idx[S0];
#pragma unroll
            for (int j = 0; j < S0; ++j) idx[j] = nb[j];
            float4 sv = ((const float4*)(feat + (size_t)self_idx * D))[lane];
            float4 v[S0];
#pragma unroll
            for (int j = 0; j < S0; ++j)
                v[j] = ((const float4*)(feat + (size_t)idx[j] * D))[lane];
            __builtin_amdgcn_sched_barrier(0);
            float4 acc = make_float4(0.f, 0.f, 0.f, 0.f);
#pragma unroll
            for (int j = 0; j < S0; ++j) {
                acc.x += v[j].x; acc.y += v[j].y; acc.z += v[j].z; acc.w += v[j].w;
            }
            const float s25 = 1.0f / 25.0f;
            bf16x4 svb = { (__bf16)sv.x, (__bf16)sv.y, (__bf16)sv.z, (__bf16)sv.w };
            bf16x4 avb = { (__bf16)(acc.x * s25), (__bf16)(acc.y * s25),
                           (__bf16)(acc.z * s25), (__bf16)(acc.w * s25) };
            const int sw = r & 7;
            const int gs = (lane >> 1) ^ sw;
            const int ga = (32 + (lane >> 1)) ^ sw;
            *(bf16x4*)(Atile + (size_t)r * 512 + gs * 8 + (lane & 1) * 4) = svb;
            *(bf16x4*)(Atile + (size_t)r * 512 + ga * 8 + (lane & 1) * 4) = avb;
            // publish row: drain LDS writes, then release increment
            asm volatile("s_waitcnt lgkmcnt(0)" ::: "memory");
            if (lane == 0)
                __hip_atomic_fetch_add(&rowcnt, 1, __ATOMIC_RELEASE, WG);
        }
        return;   // producers exit; no barriers below
    }

    // ================= consumers: waves 4..7 ==============================
    const int cw = w - 4;                  // 0..3, cols [64cw, 64cw+64)
    const int ctid = tid - 256;            // 0..255

    // W0 fp32 prefetch regs (4 slots x 32B) + stage Bs[0] for k0=0
    float4 rb0[4], rb1[4];
#pragma unroll
    for (int s = 0; s < 4; ++s) {
        int i = ctid + s * 256;
        int cg = i >> 6, kc = (i >> 4) & 3, lo = i & 15;
        const float* p = W0 + (size_t)(cg * 16 + lo) * K2 + kc * 8;
        rb0[s] = *(const float4*)p;
        rb1[s] = *(const float4*)(p + 4);
    }
#pragma unroll
    for (int s = 0; s < 4; ++s) {
        int i = ctid + s * 256;
        bf16x8 bv;
        bv[0] = (__bf16)rb0[s].x; bv[1] = (__bf16)rb0[s].y;
        bv[2] = (__bf16)rb0[s].z; bv[3] = (__bf16)rb0[s].w;
        bv[4] = (__bf16)rb1[s].x; bv[5] = (__bf16)rb1[s].y;
        bv[6] = (__bf16)rb1[s].z; bv[7] = (__bf16)rb1[s].w;
        *(bf16x8*)(&Bs[0][0] + (size_t)i * 8) = bv;
    }

    // wait for all 32 rows (acquire) -- producers never depend on us
    while (__hip_atomic_load(&rowcnt, __ATOMIC_ACQUIRE, WG) < 32)
        __builtin_amdgcn_s_sleep(2);
    __builtin_amdgcn_sched_barrier(0);

    // consumer-only round barrier (4 waves)
    int round = 0;
#define CSYNC()                                                            \
    do {                                                                   \
        ++round;                                                           \
        asm volatile("s_waitcnt lgkmcnt(0)" ::: "memory");                 \
        if (lane == 0)                                                     \
            __hip_atomic_fetch_add(&rbar, 1, __ATOMIC_RELEASE, WG);        \
        while (__hip_atomic_load(&rbar, __ATOMIC_ACQUIRE, WG) < 4 * round) \
            __builtin_amdgcn_s_sleep(1);                                   \
        __builtin_amdgcn_sched_barrier(0);                                 \
    } while (0)

    CSYNC();   // all consumers: Bs[0] staged, Atile ready

    f32x4 acc[2][4];
#pragma unroll
    for (int rf = 0; rf < 2; ++rf)
#pragma unroll
        for (int nf = 0; nf < 4; ++nf) acc[rf][nf] = (f32x4){0.f, 0.f, 0.f, 0.f};

#pragma unroll 1
    for (int t = 0; t < 16; ++t) {
        const int k0 = t * 32;
        // issue W0 prefetch for next tile early
        if (t < 15) {
#pragma unroll
            for (int s = 0; s < 4; ++s) {
                int i = ctid + s * 256;
                int cg = i >> 6, kc = (i >> 4) & 3, lo = i & 15;
                const float* p = W0 + (size_t)(cg * 16 + lo) * K2 + (k0 + 32) + kc * 8;
                rb0[s] = *(const float4*)p;
                rb1[s] = *(const float4*)(p + 4);
            }
        }
        // MFMA on Bs[t&1] + resident Atile
        {
            const int gA = (k0 >> 3) + g;
            bf16x8 af[2], bfr[4];
#pragma unroll
            for (int rf = 0; rf < 2; ++rf) {
                int row = rf * 16 + rl;
                af[rf] = *(const bf16x8*)(Atile + (size_t)row * 512 +
                                          (size_t)(gA ^ (row & 7)) * 8);
            }
#pragma unroll
            for (int nf = 0; nf < 4; ++nf)
                bfr[nf] = *(const bf16x8*)(&Bs[t & 1][0] +
                           ((size_t)((cw * 4 + nf) * 4 + g) * 16 + rl) * 8);
#pragma unroll
            for (int rf = 0; rf < 2; ++rf)
#pragma unroll
                for (int nf = 0; nf < 4; ++nf)
                    acc[rf][nf] = __builtin_amdgcn_mfma_f32_16x16x32_bf16(
                        af[rf], bfr[nf], acc[rf][nf], 0, 0, 0);
        }
        // write next Bs buffer from prefetched regs
        if (t < 15) {
#pragma unroll
            for (int s = 0; s < 4; ++s) {
                int i = ctid + s * 256;
                bf16x8 bv;
                bv[0] = (__bf16)rb0[s].x; bv[1] = (__bf16)rb0[s].y;
                bv[2] = (__bf16)rb0[s].z; bv[3] = (__bf16)rb0[s].w;
                bv[4] = (__bf16)rb1[s].x; bv[5] = (__bf16)rb1[s].y;
                bv[6] = (__bf16)rb1[s].z; bv[7] = (__bf16)rb1[s].w;
                *(bf16x8*)(&Bs[(t + 1) & 1][0] + (size_t)i * 8) = bv;
            }
        }
        CSYNC();
    }

    // ---- epilogue: bias + relu + row L2 norm + store bf16 ----
    float bv[4];
#pragma unroll
    for (int nf = 0; nf < 4; ++nf) bv[nf] = b0[cw * 64 + nf * 16 + rl];

#pragma unroll
    for (int rf = 0; rf < 2; ++rf) {
        float ss0 = 0.f, ss1 = 0.f, ss2 = 0.f, ss3 = 0.f;
#pragma unroll
        for (int nf = 0; nf < 4; ++nf) {
            float v0 = fmaxf(acc[rf][nf][0] + bv[nf], 0.f);
            float v1 = fmaxf(acc[rf][nf][1] + bv[nf], 0.f);
            float v2 = fmaxf(acc[rf][nf][2] + bv[nf], 0.f);
            float v3 = fmaxf(acc[rf][nf][3] + bv[nf], 0.f);
            acc[rf][nf][0] = v0; acc[rf][nf][1] = v1;
            acc[rf][nf][2] = v2; acc[rf][nf][3] = v3;
            ss0 += v0 * v0; ss1 += v1 * v1; ss2 += v2 * v2; ss3 += v3 * v3;
        }
#pragma unroll
        for (int m = 1; m < 16; m <<= 1) {
            ss0 += __shfl_xor(ss0, m);
            ss1 += __shfl_xor(ss1, m);
            ss2 += __shfl_xor(ss2, m);
            ss3 += __shfl_xor(ss3, m);
        }
        float ssv = (rl == 0) ? ss0 : (rl == 1) ? ss1 : (rl == 2) ? ss2 : ss3;
        if (rl < 4) ssLDS[cw][rf * 16 + g * 4 + rl] = ssv;
    }
    CSYNC();   // partials visible to all consumers
#pragma unroll
    for (int rf = 0; rf < 2; ++rf)
#pragma unroll
        for (int j = 0; j < 4; ++j) {
            const int row = rf * 16 + g * 4 + j;
            float t = ssLDS[0][row] + ssLDS[1][row] + ssLDS[2][row] + ssLDS[3][row];
            const float inv = (t > 0.f) ? rsqrtf(t) : 1.0f;
#pragma unroll
            for (int nf = 0; nf < 4; ++nf)
                h1b[(size_t)(row0 + row) * D + cw * 64 + nf * 16 + rl] =
                    (__bf16)(acc[rf][nf][j] * inv);
        }
#undef CSYNC
}

// ---------------------------------------------------------------------------
// fused_layer1 (unchanged, ~9-10us): Out[1024][256] = l2norm(relu(X1 @ W1^T
// + b1)), X1 row i = [h1[i] | mean_j h1[1024+i*10+j]] built on the fly in
// A-staging (h1 bf16). B staged from fp32 W1 with inline cvt + reg prefetch.
// ---------------------------------------------------------------------------
__global__ __launch_bounds__(256, 2) void fused_layer1(
        const __bf16* __restrict__ h1, const float* __restrict__ W1,
        const float* __restrict__ b1, float* __restrict__ Out) {
    constexpr int RB = 32;
    __shared__ __bf16 As[RB * 64];
    __shared__ __bf16 Bs[256 * 64];
    __shared__ float ssLDS[4][RB];
    __shared__ float invLDS[RB];

    const int tid = threadIdx.x;
    const int row0 = blockIdx.x * RB;
    const int lane = tid & 63;
    const int w = tid >> 6;
    const int rl = lane & 15;
    const int g = lane >> 4;
    const int rg = tid >> 7, kc8 = (tid >> 4) & 7, lo = tid & 15;
    const int grow = row0 + rg * 16 + lo;

    float4 rb0[8], rb1[8];
#pragma unroll
    for (int s = 0; s < 8; ++s) {
        int i = tid + s * 256;
        int cg = i >> 7, kc = (i >> 4) & 7, blo = i & 15;
        const float* p = W1 + (size_t)(cg * 16 + blo) * K2 + kc * 8;
        rb0[s] = *(const float4*)p;
        rb1[s] = *(const float4*)(p + 4);
    }

    f32x4 acc[2][4];
#pragma unroll
    for (int rf = 0; rf < 2; ++rf)
#pragma unroll
        for (int nf = 0; nf < 4; ++nf) acc[rf][nf] = (f32x4){0.f, 0.f, 0.f, 0.f};

    for (int k0 = 0; k0 < K2; k0 += 64) {
        bf16x8 av;
        if (k0 < 256) {
            av = *(const bf16x8*)(h1 + (size_t)grow * D + k0 + kc8 * 8);
        } else {
            float f[8];
#pragma unroll
            for (int e = 0; e < 8; ++e) f[e] = 0.f;
            const __bf16* base = h1 + (size_t)(BATCH + grow * S1) * D + (k0 - 256) + kc8 * 8;
#pragma unroll
            for (int j = 0; j < S1; ++j) {
                bf16x8 vv = *(const bf16x8*)(base + (size_t)j * D);
#pragma unroll
                for (int e = 0; e < 8; ++e) f[e] += (float)vv[e];
            }
#pragma unroll
            for (int e = 0; e < 8; ++e) av[e] = (__bf16)(f[e] * 0.1f);
        }
        *(bf16x8*)(As + (size_t)tid * 8) = av;
#pragma unroll
        for (int s = 0; s < 8; ++s) {
            int i = tid + s * 256;
            bf16x8 bb;
            bb[0] = (__bf16)rb0[s].x; bb[1] = (__bf16)rb0[s].y;
            bb[2] = (__bf16)rb0[s].z; bb[3] = (__bf16)rb0[s].w;
            bb[4] = (__bf16)rb1[s].x; bb[5] = (__bf16)rb1[s].y;
            bb[6] = (__bf16)rb1[s].z; bb[7] = (__bf16)rb1[s].w;
            *(bf16x8*)(Bs + (size_t)i * 8) = bb;
        }
        __syncthreads();
        if (k0 + 64 < K2) {
#pragma unroll
            for (int s = 0; s < 8; ++s) {
                int i = tid + s * 256;
                int cg = i >> 7, kc = (i >> 4) & 7, blo = i & 15;
                const float* p = W1 + (size_t)(cg * 16 + blo) * K2 + (k0 + 64) + kc * 8;
                rb0[s] = *(const float4*)p;
                rb1[s] = *(const float4*)(p + 4);
            }
        }
#pragma unroll
        for (int kf = 0; kf < 2; ++kf) {
            const int kc = kf * 4 + g;
            bf16x8 af[2], bfr[4];
#pragma unroll
            for (int rf = 0; rf < 2; ++rf)
                af[rf] = *(const bf16x8*)(As + ((size_t)(rf * 8 + kc) * 16 + rl) * 8);
#pragma unroll
            for (int nf = 0; nf < 4; ++nf)
                bfr[nf] = *(const bf16x8*)(Bs + ((size_t)((w * 4 + nf) * 8 + kc) * 16 + rl) * 8);
#pragma unroll
            for (int rf = 0; rf < 2; ++rf)
#pragma unroll
                for (int nf = 0; nf < 4; ++nf)
                    acc[rf][nf] = __builtin_amdgcn_mfma_f32_16x16x32_bf16(
                        af[rf], bfr[nf], acc[rf][nf], 0, 0, 0);
        }
        __syncthreads();
    }

    float bv[4];
#pragma unroll
    for (int nf = 0; nf < 4; ++nf) bv[nf] = b1[w * 64 + nf * 16 + rl];

#pragma unroll
    for (int rf = 0; rf < 2; ++rf) {
        float ss0 = 0.f, ss1 = 0.f, ss2 = 0.f, ss3 = 0.f;
#pragma unroll
        for (int nf = 0; nf < 4; ++nf) {
            float v0 = fmaxf(acc[rf][nf][0] + bv[nf], 0.f);
            float v1 = fmaxf(acc[rf][nf][1] + bv[nf], 0.f);
            float v2 = fmaxf(acc[rf][nf][2] + bv[nf], 0.f);
            float v3 = fmaxf(acc[rf][nf][3] + bv[nf], 0.f);
            acc[rf][nf][0] = v0; acc[rf][nf][1] = v1;
            acc[rf][nf][2] = v2; acc[rf][nf][3] = v3;
            ss0 += v0 * v0; ss1 += v1 * v1; ss2 += v2 * v2; ss3 += v3 * v3;
        }
#pragma unroll
        for (int m = 1; m < 16; m <<= 1) {
            ss0 += __shfl_xor(ss0, m);
            ss1 += __shfl_xor(ss1, m);
            ss2 += __shfl_xor(ss2, m);
            ss3 += __shfl_xor(ss3, m);
        }
        float ssv = (rl == 0) ? ss0 : (rl == 1) ? ss1 : (rl == 2) ? ss2 : ss3;
        if (rl < 4) ssLDS[w][rf * 16 + g * 4 + rl] = ssv;
    }
    __syncthreads();
    if (tid < RB) {
        float t = ssLDS[0][tid] + ssLDS[1][tid] + ssLDS[2][tid] + ssLDS[3][tid];
        invLDS[tid] = (t > 0.f) ? rsqrtf(t) : 1.0f;
    }
    __syncthreads();
#pragma unroll
    for (int rf = 0; rf < 2; ++rf)
#pragma unroll
        for (int j = 0; j < 4; ++j) {
            const int row = rf * 16 + g * 4 + j;
            const float inv = invLDS[row];
#pragma unroll
            for (int nf = 0; nf < 4; ++nf)
                Out[(size_t)(row0 + row) * D + w * 64 + nf * 16 + rl] = acc[rf][nf][j] * inv;
        }
}

// ---------------------------------------------------------------------------
extern "C" void kernel_launch(void* const* d_in, const int* in_sizes, int n_in,
                              void* d_out, int out_size, void* d_ws, size_t ws_size,
                              hipStream_t stream) {
    const float* features = (const float*)d_in[0];
    const float* W0       = (const float*)d_in[1];
    const float* b0       = (const float*)d_in[2];
    const float* W1       = (const float*)d_in[3];
    const float* b1       = (const float*)d_in[4];
    const int*   nodes2   = (const int*)d_in[5];
    const int*   neigh2   = (const int*)d_in[6];
    const int*   neigh1   = (const int*)d_in[7];
    float* out = (float*)d_out;

    __bf16* h1b = (__bf16*)d_ws;   // 11264*256*2 = 5.75 MB

    fused_layer0_pc<<<N1 / 32, 512, 0, stream>>>(features, W0, b0, nodes2,
                                                 neigh2, neigh1, h1b);
    fused_layer1<<<BATCH / 32, 256, 0, stream>>>(h1b, W1, b1, out);
}